// Round 10
// baseline (500.505 us; speedup 1.0000x reference)
//
#include <hip/hip_runtime.h>

#define NNODES 50000
#define NEDGES 600000
#define HID 128
#define NLAYERS 4
#define NOUT 8
#define BN_EPS 1e-5f
#define NRANGE 4
#define RSPAN 12500                 // NNODES / NRANGE; 12500*256B = 3.2 MB slice (fits 4MB XCD L2)
#define N4 (NRANGE * NNODES)        // 200000 ranged-CSR counters
#define NBLK4 782                   // ceil(N4/256)
#define NPBLK 1563                  // ceil(NNODES/32) 32-row layer blocks

typedef short short8 __attribute__((ext_vector_type(8)));
typedef float f32x4 __attribute__((ext_vector_type(4)));

__device__ inline unsigned short f2bf(float f) {
  unsigned u = __float_as_uint(f);
  unsigned r = ((u >> 16) & 1u) + 0x7fffu;
  return (unsigned short)((u + r) >> 16);
}
__device__ inline float bflo(unsigned w) { return __uint_as_float(w << 16); }
__device__ inline float bfhi(unsigned w) { return __uint_as_float(w & 0xffff0000u); }

// ---------------- utility kernels ----------------

// Detect whether edge_index arrived as int64 (odd int32 words all zero) or int32.
__global__ void detect64_k(const int* __restrict__ ei, int* __restrict__ flag) {
  __shared__ int anynz;
  if (threadIdx.x == 0) anynz = 0;
  __syncthreads();
  int acc = 0;
  for (int i = threadIdx.x; i < 4096; i += 256) {
    int p = i * 146;
    acc |= ei[2 * p + 1];
  }
  if (acc != 0) anynz = 1;
  __syncthreads();
  if (threadIdx.x == 0) *flag = (anynz == 0) ? 1 : 0;  // 1 => int64 layout
}

// fp32 -> bf16 convert (for the input x gather table)
__global__ void cvt_bf_k(const float* __restrict__ src, unsigned short* __restrict__ dst,
                         int n4) {
  int i = blockIdx.x * 256 + threadIdx.x;
  if (i >= n4) return;
  float4 v = ((const float4*)src)[i];
  ushort4 o;
  o.x = f2bf(v.x);
  o.y = f2bf(v.y);
  o.z = f2bf(v.z);
  o.w = f2bf(v.w);
  ((ushort4*)dst)[i] = o;
}

// ---------------- ranged CSR build: counters laid out [range][node] ----------------

__global__ void zero_deg_k(int* __restrict__ deg) {
  int i = blockIdx.x * 256 + threadIdx.x;
  if (i < N4) deg[i] = 0;
}

__global__ void hist_k(const int* __restrict__ ei, const int* __restrict__ flag,
                       int* __restrict__ deg) {
  int e = blockIdx.x * 256 + threadIdx.x;
  if (e >= NEDGES) return;
  int s, d;
  if (*flag) {
    s = ei[2 * e];
    d = ei[2 * NEDGES + 2 * e];
  } else {
    s = ei[e];
    d = ei[NEDGES + e];
  }
  atomicAdd(&deg[(s / RSPAN) * NNODES + d], 1);
}

// Parallel scan, phase A: per-256-chunk sums.
__global__ void blocksum_k(const int* __restrict__ deg, int* __restrict__ bsum) {
  int t = threadIdx.x;
  int i = blockIdx.x * 256 + t;
  __shared__ int sh[256];
  sh[t] = (i < N4) ? deg[i] : 0;
  __syncthreads();
  for (int s = 128; s > 0; s >>= 1) {
    if (t < s) sh[t] += sh[t + s];
    __syncthreads();
  }
  if (t == 0) bsum[blockIdx.x] = sh[0];
}

// Phase B: single-block exclusive scan of the NBLK4 block sums.
__global__ __launch_bounds__(1024) void scanb_k(const int* __restrict__ bsum,
                                                int* __restrict__ boff) {
  __shared__ int sh[1024];
  int t = threadIdx.x;
  sh[t] = (t < NBLK4) ? bsum[t] : 0;
  __syncthreads();
  for (int d = 1; d < 1024; d <<= 1) {
    int v = (t >= d) ? sh[t - d] : 0;
    __syncthreads();
    sh[t] += v;
    __syncthreads();
  }
  if (t < NBLK4) boff[t] = (t == 0) ? 0 : sh[t - 1];
}

// Phase C: per-block exclusive scan + block offset -> off/cursor.
__global__ void writeoff_k(const int* __restrict__ deg, const int* __restrict__ boff,
                           int* __restrict__ off, int* __restrict__ cursor) {
  int t = threadIdx.x;
  int i = blockIdx.x * 256 + t;
  __shared__ int sh[256];
  int v = (i < N4) ? deg[i] : 0;
  sh[t] = v;
  __syncthreads();
  for (int d = 1; d < 256; d <<= 1) {
    int u = (t >= d) ? sh[t - d] : 0;
    __syncthreads();
    sh[t] += u;
    __syncthreads();
  }
  int excl = boff[blockIdx.x] + sh[t] - v;
  if (i < N4) {
    off[i] = excl;
    cursor[i] = excl;
  }
  if (i == N4 - 1) off[N4] = excl + v;
}

__global__ void fill_k(const int* __restrict__ ei, const int* __restrict__ flag,
                       int* __restrict__ cursor, int* __restrict__ srcs) {
  int e = blockIdx.x * 256 + threadIdx.x;
  if (e >= NEDGES) return;
  int s, d;
  if (*flag) {
    s = ei[2 * e];
    d = ei[2 * NEDGES + 2 * e];
  } else {
    s = ei[e];
    d = ei[NEDGES + e];
  }
  int pos = atomicAdd(&cursor[(s / RSPAN) * NNODES + d], 1);
  srcs[pos] = s;
}

// ---------------- weight pre-pack into MFMA B-fragment layout ----------------
__global__ void packW_k(const float* __restrict__ W1, const float* __restrict__ W2,
                        const float* __restrict__ L1, unsigned short* __restrict__ P) {
  int t = blockIdx.x * 256 + threadIdx.x;
  if (t >= 48 * 512) return;
  int gk = t >> 9;
  int nt = (t >> 6) & 7;
  int lane = t & 63;
  const float* src;
  int kbase;
  if (gk < 16) {
    src = W1 + (gk >> 2) * 16384;
    kbase = (gk & 3) * 32;
  } else if (gk < 32) {
    src = W2 + ((gk - 16) >> 2) * 16384;
    kbase = ((gk - 16) & 3) * 32;
  } else {
    src = L1;
    kbase = (gk - 32) * 32;
  }
  int n = nt * 16 + (lane & 15);
  int k0 = kbase + (lane >> 4) * 8;
  unsigned short* dst = P + (size_t)t * 8;
#pragma unroll
  for (int j = 0; j < 8; ++j) dst[j] = f2bf(src[(size_t)(k0 + j) * HID + n]);
}

// ---------------- fused layer: ranged gather-agg + 2-stage MLP + BN stat partials ----
// 128 threads, 32 nodes/block. Phase A: gather with src-range outer loop (L2-resident
// slices), fp32 accum in LDS. Then cvt to bf16 slab (overlaid), MFMA stages as before.
__global__ __launch_bounds__(128) void layer_k(const unsigned short* __restrict__ X,
                                               const int* __restrict__ off,
                                               const int* __restrict__ srcs,
                                               const unsigned short* __restrict__ P1,
                                               const float* __restrict__ bias1,
                                               const unsigned short* __restrict__ P2,
                                               const float* __restrict__ bias2,
                                               float* __restrict__ H, int M,
                                               float* __restrict__ pstats) {
  // smem overlay: [0,16896) fp32 agg[32][132]  ->  [0,8704) bf16 slab[32][136]
  //               + [8704,17408) per-wave sA[2][16][136]
  __shared__ __align__(16) char smem[17408];
  __shared__ float sSum[128], sSq[128];
  int tid = threadIdx.x;
  sSum[tid] = 0.f;
  sSq[tid] = 0.f;

  // ---- phase A: ranged gather-aggregate (fp32, LDS) ----
  float(*aggF)[132] = (float(*)[132])smem;
  const uint2* Xv = (const uint2*)X;
  int g = tid >> 5, gl = tid & 31;
  for (int r = 0; r < NRANGE; ++r) {
    const int* offR = off + r * NNODES;
#pragma unroll
    for (int s8 = 0; s8 < 8; ++s8) {
      int slot = s8 * 4 + g;
      int node = blockIdx.x * 32 + slot;
      if (node > M - 1) node = M - 1;
      float a0, a1, a2, a3;
      if (r == 0) {  // GIN self term
        uint2 sv = Xv[(size_t)node * 32 + gl];
        a0 = bflo(sv.x); a1 = bfhi(sv.x); a2 = bflo(sv.y); a3 = bfhi(sv.y);
      } else {
        float4 pv = *(const float4*)&aggF[slot][gl * 4];
        a0 = pv.x; a1 = pv.y; a2 = pv.z; a3 = pv.w;
      }
      int bnd = offR[node + 1];
      for (int base = offR[node]; base < bnd; base += 32) {
        int cnt = bnd - base;
        if (cnt > 32) cnt = 32;
        int idx = (gl < cnt) ? srcs[base + gl] : 0;
#pragma unroll 4
        for (int i = 0; i < cnt; ++i) {
          int s = __shfl(idx, i, 32);
          uint2 v = Xv[(size_t)s * 32 + gl];
          a0 += bflo(v.x); a1 += bfhi(v.x); a2 += bflo(v.y); a3 += bfhi(v.y);
        }
      }
      *(float4*)&aggF[slot][gl * 4] = make_float4(a0, a1, a2, a3);
    }
  }
  __syncthreads();

  // ---- cvt fp32 agg -> bf16 slab (in-place overlay; read-all, sync, write) ----
  float tv[32];
  int crow = tid >> 2, ccol = (tid & 3) * 32;
#pragma unroll
  for (int j = 0; j < 32; ++j) tv[j] = aggF[crow][ccol + j];
  __syncthreads();
  unsigned short* slab = (unsigned short*)smem;  // [32][136]
#pragma unroll
  for (int j = 0; j < 32; ++j) slab[crow * 136 + ccol + j] = f2bf(tv[j]);
  __syncthreads();

  // ---- MFMA stage 1 ----
  int lane = tid & 63, w = tid >> 6;
  int rb = blockIdx.x * 32 + w * 16;
  int hi = lane >> 4, c = lane & 15;
  int koff = hi * 8;
  int arow = w * 16 + c;
  const short8* Bp1 = (const short8*)P1;
  f32x4 acc[8];
#pragma unroll
  for (int nt = 0; nt < 8; ++nt) acc[nt] = (f32x4){0.f, 0.f, 0.f, 0.f};
  short8 bcur[8], bnxt[8];
#pragma unroll
  for (int nt = 0; nt < 8; ++nt) bcur[nt] = Bp1[nt * 64 + lane];
#pragma unroll
  for (int ks = 0; ks < 4; ++ks) {
    short8 af = *(const short8*)&slab[arow * 136 + ks * 32 + koff];
    if (ks < 3) {
#pragma unroll
      for (int nt = 0; nt < 8; ++nt) bnxt[nt] = Bp1[(ks + 1) * 512 + nt * 64 + lane];
    }
#pragma unroll
    for (int nt = 0; nt < 8; ++nt)
      acc[nt] = __builtin_amdgcn_mfma_f32_16x16x32_bf16(af, bcur[nt], acc[nt], 0, 0, 0);
    if (ks < 3) {
#pragma unroll
      for (int nt = 0; nt < 8; ++nt) bcur[nt] = bnxt[nt];
    }
  }
  // epilogue 1: relu + bf16 -> per-wave sA slab
  unsigned short* sAw = ((unsigned short*)smem) + 4352 + w * 2176;  // 16*136
#pragma unroll
  for (int nt = 0; nt < 8; ++nt) {
    int col = nt * 16 + c;
    float b = bias1[col];
#pragma unroll
    for (int rr = 0; rr < 4; ++rr) {
      float v = fmaxf(acc[nt][rr] + b, 0.f);
      sAw[(hi * 4 + rr) * 136 + col] = f2bf(v);
    }
  }
  __syncthreads();

  // ---- MFMA stage 2 ----
#pragma unroll
  for (int nt = 0; nt < 8; ++nt) acc[nt] = (f32x4){0.f, 0.f, 0.f, 0.f};
  const short8* Bp2 = (const short8*)P2;
#pragma unroll
  for (int nt = 0; nt < 8; ++nt) bcur[nt] = Bp2[nt * 64 + lane];
#pragma unroll
  for (int ks = 0; ks < 4; ++ks) {
    short8 af = *(const short8*)&sAw[c * 136 + ks * 32 + koff];
    if (ks < 3) {
#pragma unroll
      for (int nt = 0; nt < 8; ++nt) bnxt[nt] = Bp2[(ks + 1) * 512 + nt * 64 + lane];
    }
#pragma unroll
    for (int nt = 0; nt < 8; ++nt)
      acc[nt] = __builtin_amdgcn_mfma_f32_16x16x32_bf16(af, bcur[nt], acc[nt], 0, 0, 0);
    if (ks < 3) {
#pragma unroll
      for (int nt = 0; nt < 8; ++nt) bcur[nt] = bnxt[nt];
    }
  }
  // epilogue 2: relu + fp32 write + BN stat partials
#pragma unroll
  for (int nt = 0; nt < 8; ++nt) {
    int col = nt * 16 + c;
    float b = bias2[col];
    float s = 0.f, q = 0.f;
#pragma unroll
    for (int rr = 0; rr < 4; ++rr) {
      int row = rb + hi * 4 + rr;
      if (row < M) {
        float v = fmaxf(acc[nt][rr] + b, 0.f);
        H[(size_t)row * HID + col] = v;
        s += v;
        q += v * v;
      }
    }
    s += __shfl_xor(s, 16, 64);
    q += __shfl_xor(q, 16, 64);
    s += __shfl_xor(s, 32, 64);
    q += __shfl_xor(q, 32, 64);
    if (hi == 0) {
      atomicAdd(&sSum[col], s);  // LDS atomics, 2 waves only
      atomicAdd(&sSq[col], q);
    }
  }
  __syncthreads();
  {
    float* dst = pstats + (size_t)blockIdx.x * 256;
    dst[tid] = sSum[tid];
    dst[128 + tid] = sSq[tid];
  }
}

// ---------------- stats finalize: stats[j] = sum_b pstats[b][j] ----------------
__global__ void reduce_stats_k(const float* __restrict__ pstats, float* __restrict__ stats) {
  __shared__ float sh[256];
  int j = blockIdx.x;
  int t = threadIdx.x;
  float acc = 0.f;
  for (int b = t; b < NPBLK; b += 256) acc += pstats[(size_t)b * 256 + j];
  sh[t] = acc;
  __syncthreads();
  for (int s = 128; s > 0; s >>= 1) {
    if (t < s) sh[t] += sh[t + s];
    __syncthreads();
  }
  if (t == 0) stats[j] = sh[0];
}

// ---------------- MFMA JK GEMM: t2 = relu(concat(hb0..hb3) @ lin1_W + b), fp32 out ----
__global__ __launch_bounds__(128) void mjkgemm_k(const unsigned short* __restrict__ H0,
                                                 const unsigned short* __restrict__ H1,
                                                 const unsigned short* __restrict__ H2,
                                                 const unsigned short* __restrict__ H3,
                                                 const unsigned short* __restrict__ P,
                                                 const float* __restrict__ bias,
                                                 float* __restrict__ C, int M) {
  int tid = threadIdx.x;
  int lane = tid & 63, w = tid >> 6;
  int rb = blockIdx.x * 32 + w * 16;
  int r = rb + (lane & 15);
  if (r > M - 1) r = M - 1;
  int koff = (lane >> 4) * 8;
  f32x4 acc[8];
#pragma unroll
  for (int nt = 0; nt < 8; ++nt) acc[nt] = (f32x4){0.f, 0.f, 0.f, 0.f};
  const unsigned short* Hs[4] = {H0, H1, H2, H3};
  short8 bcur[8], bnxt[8];
  for (int l = 0; l < 4; ++l) {
    const short8* Bp = (const short8*)(P + l * 16384);
    short8 a_[4];
    const unsigned short* Ar = Hs[l] + (size_t)r * HID + koff;
#pragma unroll
    for (int ks = 0; ks < 4; ++ks) a_[ks] = *(const short8*)(Ar + ks * 32);
#pragma unroll
    for (int nt = 0; nt < 8; ++nt) bcur[nt] = Bp[nt * 64 + lane];
#pragma unroll
    for (int ks = 0; ks < 4; ++ks) {
      if (ks < 3) {
#pragma unroll
        for (int nt = 0; nt < 8; ++nt) bnxt[nt] = Bp[(ks + 1) * 512 + nt * 64 + lane];
      }
#pragma unroll
      for (int nt = 0; nt < 8; ++nt)
        acc[nt] = __builtin_amdgcn_mfma_f32_16x16x32_bf16(a_[ks], bcur[nt], acc[nt], 0, 0, 0);
      if (ks < 3) {
#pragma unroll
        for (int nt = 0; nt < 8; ++nt) bcur[nt] = bnxt[nt];
      }
    }
  }
  int hi = lane >> 4, c = lane & 15;
#pragma unroll
  for (int nt = 0; nt < 8; ++nt) {
    int col = nt * 16 + c;
    float b = bias[col];
#pragma unroll
    for (int rr = 0; rr < 4; ++rr) {
      int row = rb + hi * 4 + rr;
      if (row < M) {
        float v = fmaxf(acc[nt][rr] + b, 0.f);
        C[(size_t)row * HID + col] = v;
      }
    }
  }
}

// ---------------- BatchNorm normalize: fp32 h -> bf16 hb ----------------
__global__ void bn_norm_k(const float* __restrict__ H, unsigned short* __restrict__ HB,
                          const float* __restrict__ stats, const float* __restrict__ gamma,
                          const float* __restrict__ beta) {
  int i = blockIdx.x * 256 + threadIdx.x;
  if (i >= NNODES * 32) return;
  int c4 = i & 31;
  float4 v = ((const float4*)H)[i];
  float4 sm = ((const float4*)stats)[c4];
  float4 sq = ((const float4*)(stats + 128))[c4];
  float4 g = ((const float4*)gamma)[c4];
  float4 bt = ((const float4*)beta)[c4];
  const float invN = 1.0f / (float)NNODES;
  float m, var, inv;
  ushort4 o;
  m = sm.x * invN; var = sq.x * invN - m * m; inv = rsqrtf(var + BN_EPS);
  o.x = f2bf((v.x - m) * inv * g.x + bt.x);
  m = sm.y * invN; var = sq.y * invN - m * m; inv = rsqrtf(var + BN_EPS);
  o.y = f2bf((v.y - m) * inv * g.y + bt.y);
  m = sm.z * invN; var = sq.z * invN - m * m; inv = rsqrtf(var + BN_EPS);
  o.z = f2bf((v.z - m) * inv * g.z + bt.z);
  m = sm.w * invN; var = sq.w * invN - m * m; inv = rsqrtf(var + BN_EPS);
  o.w = f2bf((v.w - m) * inv * g.w + bt.w);
  ((ushort4*)HB)[i] = o;
}

// ---------------- head: out[M,8] = t2[M,128] @ W[128,8] + b ----------------
__global__ void head_k(const float* __restrict__ O1, const float* __restrict__ W,
                       const float* __restrict__ b, float* __restrict__ out, int M) {
  __shared__ float sW[HID * NOUT];
  int tid = threadIdx.x;
#pragma unroll
  for (int i = 0; i < 4; ++i) sW[tid + i * 256] = W[tid + i * 256];
  __syncthreads();
  int row = blockIdx.x * 256 + tid;
  if (row >= M) return;
  float acc[NOUT];
#pragma unroll
  for (int j = 0; j < NOUT; ++j) acc[j] = b[j];
  const float* Ar = O1 + (size_t)row * HID;
  for (int k = 0; k < HID; k += 4) {
    float4 a = *(const float4*)(Ar + k);
#pragma unroll
    for (int kk = 0; kk < 4; ++kk) {
      float av = ((const float*)&a)[kk];
#pragma unroll
      for (int j = 0; j < NOUT; ++j) acc[j] += av * sW[(k + kk) * NOUT + j];
    }
  }
#pragma unroll
  for (int j = 0; j < NOUT; ++j) out[(size_t)row * NOUT + j] = acc[j];
}

// ---------------- launch ----------------

extern "C" void kernel_launch(void* const* d_in, const int* in_sizes, int n_in,
                              void* d_out, int out_size, void* d_ws, size_t ws_size,
                              hipStream_t stream) {
  const float* x     = (const float*)d_in[0];
  const int*   ei    = (const int*)d_in[1];
  const float* W1    = (const float*)d_in[2];
  const float* b1    = (const float*)d_in[3];
  const float* W2    = (const float*)d_in[4];
  const float* b2    = (const float*)d_in[5];
  const float* gamma = (const float*)d_in[6];
  const float* beta  = (const float*)d_in[7];
  const float* l1W   = (const float*)d_in[8];
  const float* l1b   = (const float*)d_in[9];
  const float* l2W   = (const float*)d_in[10];
  const float* l2b   = (const float*)d_in[11];

  float* ws = (float*)d_ws;
  const size_t NB = (size_t)NNODES * HID;  // 6.4e6 elements
  const size_t NBH = NB / 2;               // bf16 buffer in float units
  float* h = ws;                           // fp32 pre-BN (reused each layer)
  float* t2 = ws + NB;                     // fp32 jk output
  unsigned short* xb = (unsigned short*)(ws + 2 * NB);  // bf16 x
  unsigned short* hb[4];
  for (int l = 0; l < 4; ++l)
    hb[l] = (unsigned short*)(ws + 2 * NB + (1 + l) * NBH);  // bf16 post-BN
  float* stats = ws + 2 * NB + 5 * NBH;
  int* flag = (int*)(stats + 1024);
  int* deg = flag + 4;
  int* off = deg + N4;
  int* cursor = off + (N4 + 1);
  int* bsum = cursor + (N4 + 1);
  int* boff = bsum + 1024;
  int* srcs = boff + 1024;
  size_t pofs = 2 * NB + 5 * NBH + 1024 + 4 + N4 + 2 * (size_t)(N4 + 1) + 2048 + NEDGES;
  pofs = (pofs + 3) & ~(size_t)3;  // 16B align
  unsigned short* P = (unsigned short*)(ws + pofs);
  // P: W1 layer l at l*16384; W2 layer l at 65536 + l*16384; lin1 at 131072.
  float* pstats = ws + pofs + 98304;  // NPBLK x 256 partial stats

  detect64_k<<<1, 256, 0, stream>>>(ei, flag);
  zero_deg_k<<<NBLK4, 256, 0, stream>>>(deg);
  hist_k<<<2344, 256, 0, stream>>>(ei, flag, deg);
  blocksum_k<<<NBLK4, 256, 0, stream>>>(deg, bsum);
  scanb_k<<<1, 1024, 0, stream>>>(bsum, boff);
  writeoff_k<<<NBLK4, 256, 0, stream>>>(deg, boff, off, cursor);
  fill_k<<<2344, 256, 0, stream>>>(ei, flag, cursor, srcs);
  packW_k<<<96, 256, 0, stream>>>(W1, W2, l1W, P);
  cvt_bf_k<<<6250, 256, 0, stream>>>(x, xb, NNODES * 32);

  const unsigned short* hin = xb;
  for (int l = 0; l < NLAYERS; ++l) {
    layer_k<<<NPBLK, 128, 0, stream>>>(hin, off, srcs, P + (size_t)l * 16384, b1 + l * HID,
                                       P + 65536 + (size_t)l * 16384, b2 + l * HID, h, NNODES,
                                       pstats);
    reduce_stats_k<<<256, 256, 0, stream>>>(pstats, stats + l * 256);
    bn_norm_k<<<6250, 256, 0, stream>>>(h, hb[l], stats + l * 256, gamma + l * HID,
                                        beta + l * HID);
    hin = hb[l];
  }
  mjkgemm_k<<<NPBLK, 128, 0, stream>>>(hb[0], hb[1], hb[2], hb[3], P + 131072, l1b, t2, NNODES);
  head_k<<<196, 256, 0, stream>>>(t2, l2W, l2b, (float*)d_out, NNODES);
}

// Round 11
// 376.264 us; speedup vs baseline: 1.3302x; 1.3302x over previous
//
#include <hip/hip_runtime.h>

#define NNODES 50000
#define NEDGES 600000
#define HID 128
#define NLAYERS 4
#define NOUT 8
#define BN_EPS 1e-5f
#define NBLK 196    // ceil(NNODES/256)
#define NPBLK 3125  // NNODES/16 — 16-row MFMA blocks (2 waves, N-split)

typedef short short8 __attribute__((ext_vector_type(8)));
typedef float f32x4 __attribute__((ext_vector_type(4)));

__device__ inline unsigned short f2bf(float f) {
  unsigned u = __float_as_uint(f);
  unsigned r = ((u >> 16) & 1u) + 0x7fffu;
  return (unsigned short)((u + r) >> 16);
}
__device__ inline float bflo(unsigned w) { return __uint_as_float(w << 16); }
__device__ inline float bfhi(unsigned w) { return __uint_as_float(w & 0xffff0000u); }

// ---------------- utility kernels ----------------

// Detect whether edge_index arrived as int64 (odd int32 words all zero) or int32.
__global__ void detect64_k(const int* __restrict__ ei, int* __restrict__ flag) {
  __shared__ int anynz;
  if (threadIdx.x == 0) anynz = 0;
  __syncthreads();
  int acc = 0;
  for (int i = threadIdx.x; i < 4096; i += 256) {
    int p = i * 146;
    acc |= ei[2 * p + 1];
  }
  if (acc != 0) anynz = 1;
  __syncthreads();
  if (threadIdx.x == 0) *flag = (anynz == 0) ? 1 : 0;  // 1 => int64 layout
}

// fp32 -> bf16 convert (for the input x gather table)
__global__ void cvt_bf_k(const float* __restrict__ src, unsigned short* __restrict__ dst,
                         int n4) {
  int i = blockIdx.x * 256 + threadIdx.x;
  if (i >= n4) return;
  float4 v = ((const float4*)src)[i];
  ushort4 o;
  o.x = f2bf(v.x);
  o.y = f2bf(v.y);
  o.z = f2bf(v.z);
  o.w = f2bf(v.w);
  ((ushort4*)dst)[i] = o;
}

// ---------------- CSR build ----------------

__global__ void zero_deg_k(int* __restrict__ deg) {
  int i = blockIdx.x * 256 + threadIdx.x;
  if (i < NNODES + 1) deg[i] = 0;
}

__global__ void hist_k(const int* __restrict__ ei, const int* __restrict__ flag,
                       int* __restrict__ deg) {
  int e = blockIdx.x * 256 + threadIdx.x;
  if (e >= NEDGES) return;
  int d = (*flag) ? ei[2 * NEDGES + 2 * e] : ei[NEDGES + e];
  atomicAdd(&deg[d], 1);
}

// Parallel scan, phase A: per-block (256-chunk) sums.
__global__ void blocksum_k(const int* __restrict__ deg, int* __restrict__ bsum) {
  int t = threadIdx.x;
  int i = blockIdx.x * 256 + t;
  __shared__ int sh[256];
  sh[t] = (i < NNODES) ? deg[i] : 0;
  __syncthreads();
  for (int s = 128; s > 0; s >>= 1) {
    if (t < s) sh[t] += sh[t + s];
    __syncthreads();
  }
  if (t == 0) bsum[blockIdx.x] = sh[0];
}

// Phase B: single-block exclusive scan of the NBLK block sums.
__global__ void scanb_k(const int* __restrict__ bsum, int* __restrict__ boff) {
  __shared__ int sh[256];
  int t = threadIdx.x;
  sh[t] = (t < NBLK) ? bsum[t] : 0;
  __syncthreads();
  for (int d = 1; d < 256; d <<= 1) {
    int v = (t >= d) ? sh[t - d] : 0;
    __syncthreads();
    sh[t] += v;
    __syncthreads();
  }
  if (t < NBLK) boff[t] = (t == 0) ? 0 : sh[t - 1];
}

// Phase C: per-block exclusive scan + block offset -> off/cursor.
__global__ void writeoff_k(const int* __restrict__ deg, const int* __restrict__ boff,
                           int* __restrict__ off, int* __restrict__ cursor) {
  int t = threadIdx.x;
  int i = blockIdx.x * 256 + t;
  __shared__ int sh[256];
  int v = (i < NNODES) ? deg[i] : 0;
  sh[t] = v;
  __syncthreads();
  for (int d = 1; d < 256; d <<= 1) {
    int u = (t >= d) ? sh[t - d] : 0;
    __syncthreads();
    sh[t] += u;
    __syncthreads();
  }
  int excl = boff[blockIdx.x] + sh[t] - v;
  if (i < NNODES) {
    off[i] = excl;
    cursor[i] = excl;
  }
  if (i == NNODES - 1) off[NNODES] = excl + v;
}

__global__ void fill_k(const int* __restrict__ ei, const int* __restrict__ flag,
                       int* __restrict__ cursor, int* __restrict__ srcs) {
  int e = blockIdx.x * 256 + threadIdx.x;
  if (e >= NEDGES) return;
  int s, d;
  if (*flag) {
    s = ei[2 * e];
    d = ei[2 * NEDGES + 2 * e];
  } else {
    s = ei[e];
    d = ei[NEDGES + e];
  }
  int pos = atomicAdd(&cursor[d], 1);
  srcs[pos] = s;
}

// ---------------- fused gather-aggregate (bf16 table -> bf16 out) ----------------
__global__ void gather_agg_k(const unsigned short* __restrict__ X,
                             const int* __restrict__ off, const int* __restrict__ srcs,
                             unsigned short* __restrict__ T) {
  int gid = blockIdx.x * 256 + threadIdx.x;
  int node = gid >> 5;
  if (node >= NNODES) return;
  int lane = gid & 31;
  int a = off[node], b = off[node + 1];
  const uint2* Xv = (const uint2*)X;
  uint2 w = Xv[(size_t)node * 32 + lane];
  float a0 = bflo(w.x), a1 = bfhi(w.x), a2 = bflo(w.y), a3 = bfhi(w.y);
  for (int base = a; base < b; base += 32) {
    int cnt = b - base;
    if (cnt > 32) cnt = 32;
    int idx = (lane < cnt) ? srcs[base + lane] : 0;
#pragma unroll 8
    for (int i = 0; i < cnt; ++i) {
      int s = __shfl(idx, i, 32);
      uint2 v = Xv[(size_t)s * 32 + lane];
      a0 += bflo(v.x);
      a1 += bfhi(v.x);
      a2 += bflo(v.y);
      a3 += bfhi(v.y);
    }
  }
  uint2 o;
  o.x = (unsigned)f2bf(a0) | ((unsigned)f2bf(a1) << 16);
  o.y = (unsigned)f2bf(a2) | ((unsigned)f2bf(a3) << 16);
  ((uint2*)T)[(size_t)node * 32 + lane] = o;
}

// ---------------- weight pre-pack into MFMA B-fragment layout ----------------
__global__ void packW_k(const float* __restrict__ W1, const float* __restrict__ W2,
                        const float* __restrict__ L1, unsigned short* __restrict__ P) {
  int t = blockIdx.x * 256 + threadIdx.x;
  if (t >= 48 * 512) return;
  int gk = t >> 9;
  int nt = (t >> 6) & 7;
  int lane = t & 63;
  const float* src;
  int kbase;
  if (gk < 16) {
    src = W1 + (gk >> 2) * 16384;
    kbase = (gk & 3) * 32;
  } else if (gk < 32) {
    src = W2 + ((gk - 16) >> 2) * 16384;
    kbase = ((gk - 16) & 3) * 32;
  } else {
    src = L1;
    kbase = (gk - 32) * 32;
  }
  int n = nt * 16 + (lane & 15);
  int k0 = kbase + (lane >> 4) * 8;
  unsigned short* dst = P + (size_t)t * 8;
#pragma unroll
  for (int j = 0; j < 8; ++j) dst[j] = f2bf(src[(size_t)(k0 + j) * HID + n]);
}

// ---------------- fused MLP: H = relu(relu(A@W1+b1)@W2+b2); stats -> pstats ----------
// 2 waves/block, 16 rows/block (N-split: wave w owns n-tiles 4w..4w+3), grid NPBLK.
// Doubles wave-level parallelism vs 16-row-per-wave layout (24 vs 12 waves/CU).
__global__ __launch_bounds__(128) void mlp_k(const unsigned short* __restrict__ A,
                                             const unsigned short* __restrict__ P1,
                                             const float* __restrict__ bias1,
                                             const unsigned short* __restrict__ P2,
                                             const float* __restrict__ bias2,
                                             float* __restrict__ H, int M,
                                             float* __restrict__ pstats) {
  __shared__ unsigned short sA[16 * 136];  // 16x128 stage1->stage2 slab (+pad)
  int tid = threadIdx.x;
  int lane = tid & 63, w = tid >> 6;
  int rb = blockIdx.x * 16;  // NNODES % 16 == 0: no tail clamp needed
  int r = rb + (lane & 15);
  int hi = lane >> 4, c = lane & 15;
  int koff = hi * 8;
  int ntb = w * 4;  // this wave's n-tile base (cols 64w..64w+63)

  // hoisted A-row loads
  short8 a_[4];
  const unsigned short* Ar = A + (size_t)r * HID + koff;
#pragma unroll
  for (int ks = 0; ks < 4; ++ks) a_[ks] = *(const short8*)(Ar + ks * 32);

  const short8* Bp1 = (const short8*)P1;
  f32x4 acc[4];
#pragma unroll
  for (int nt = 0; nt < 4; ++nt) acc[nt] = (f32x4){0.f, 0.f, 0.f, 0.f};
  short8 bcur[4], bnxt[4];
#pragma unroll
  for (int nt = 0; nt < 4; ++nt) bcur[nt] = Bp1[(ntb + nt) * 64 + lane];
#pragma unroll
  for (int ks = 0; ks < 4; ++ks) {
    if (ks < 3) {
#pragma unroll
      for (int nt = 0; nt < 4; ++nt) bnxt[nt] = Bp1[(ks + 1) * 512 + (ntb + nt) * 64 + lane];
    }
#pragma unroll
    for (int nt = 0; nt < 4; ++nt)
      acc[nt] = __builtin_amdgcn_mfma_f32_16x16x32_bf16(a_[ks], bcur[nt], acc[nt], 0, 0, 0);
    if (ks < 3) {
#pragma unroll
      for (int nt = 0; nt < 4; ++nt) bcur[nt] = bnxt[nt];
    }
  }
  // epilogue 1: relu + bf16 -> shared slab (wave-disjoint column halves)
#pragma unroll
  for (int nt = 0; nt < 4; ++nt) {
    int col = (ntb + nt) * 16 + c;
    float b = bias1[col];
#pragma unroll
    for (int rr = 0; rr < 4; ++rr) {
      float v = fmaxf(acc[nt][rr] + b, 0.f);
      sA[(hi * 4 + rr) * 136 + col] = f2bf(v);
    }
  }
  __syncthreads();

  // stage 2: A from slab (full k), B2 for own n-tiles
#pragma unroll
  for (int nt = 0; nt < 4; ++nt) acc[nt] = (f32x4){0.f, 0.f, 0.f, 0.f};
  const short8* Bp2 = (const short8*)P2;
#pragma unroll
  for (int nt = 0; nt < 4; ++nt) bcur[nt] = Bp2[(ntb + nt) * 64 + lane];
#pragma unroll
  for (int ks = 0; ks < 4; ++ks) {
    short8 af = *(const short8*)&sA[c * 136 + ks * 32 + koff];
    if (ks < 3) {
#pragma unroll
      for (int nt = 0; nt < 4; ++nt) bnxt[nt] = Bp2[(ks + 1) * 512 + (ntb + nt) * 64 + lane];
    }
#pragma unroll
    for (int nt = 0; nt < 4; ++nt)
      acc[nt] = __builtin_amdgcn_mfma_f32_16x16x32_bf16(af, bcur[nt], acc[nt], 0, 0, 0);
    if (ks < 3) {
#pragma unroll
      for (int nt = 0; nt < 4; ++nt) bcur[nt] = bnxt[nt];
    }
  }
  // epilogue 2: relu + fp32 write + BN stat partials (wave-disjoint cols -> no atomics)
  float* dst = pstats + (size_t)blockIdx.x * 256;
#pragma unroll
  for (int nt = 0; nt < 4; ++nt) {
    int col = (ntb + nt) * 16 + c;
    float b = bias2[col];
    float s = 0.f, q = 0.f;
#pragma unroll
    for (int rr = 0; rr < 4; ++rr) {
      int row = rb + hi * 4 + rr;
      float v = fmaxf(acc[nt][rr] + b, 0.f);
      H[(size_t)row * HID + col] = v;
      s += v;
      q += v * v;
    }
    s += __shfl_xor(s, 16, 64);
    q += __shfl_xor(q, 16, 64);
    s += __shfl_xor(s, 32, 64);
    q += __shfl_xor(q, 32, 64);
    if (hi == 0) {
      dst[col] = s;  // unique writer per column
      dst[128 + col] = q;
    }
  }
}

// ---------------- stats finalize: stats[j] = sum_b pstats[b][j] ----------------
__global__ void reduce_stats_k(const float* __restrict__ pstats, float* __restrict__ stats) {
  __shared__ float sh[256];
  int j = blockIdx.x;
  int t = threadIdx.x;
  float acc = 0.f;
  for (int b = t; b < NPBLK; b += 256) acc += pstats[(size_t)b * 256 + j];
  sh[t] = acc;
  __syncthreads();
  for (int s = 128; s > 0; s >>= 1) {
    if (t < s) sh[t] += sh[t + s];
    __syncthreads();
  }
  if (t == 0) stats[j] = sh[0];
}

// ---------------- MFMA JK GEMM: t2 = relu(concat(hb0..hb3) @ lin1_W + b), fp32 out ----
// 2 waves/block, 16 rows/block, N-split as in mlp_k.
__global__ __launch_bounds__(128) void mjkgemm_k(const unsigned short* __restrict__ H0,
                                                 const unsigned short* __restrict__ H1,
                                                 const unsigned short* __restrict__ H2,
                                                 const unsigned short* __restrict__ H3,
                                                 const unsigned short* __restrict__ P,
                                                 const float* __restrict__ bias,
                                                 float* __restrict__ C, int M) {
  int tid = threadIdx.x;
  int lane = tid & 63, w = tid >> 6;
  int rb = blockIdx.x * 16;
  int r = rb + (lane & 15);
  int koff = (lane >> 4) * 8;
  int ntb = w * 4;
  f32x4 acc[4];
#pragma unroll
  for (int nt = 0; nt < 4; ++nt) acc[nt] = (f32x4){0.f, 0.f, 0.f, 0.f};
  const unsigned short* Hs[4] = {H0, H1, H2, H3};
  short8 bcur[4], bnxt[4];
  for (int l = 0; l < 4; ++l) {
    const short8* Bp = (const short8*)(P + l * 16384);
    short8 a_[4];
    const unsigned short* Ar = Hs[l] + (size_t)r * HID + koff;
#pragma unroll
    for (int ks = 0; ks < 4; ++ks) a_[ks] = *(const short8*)(Ar + ks * 32);
#pragma unroll
    for (int nt = 0; nt < 4; ++nt) bcur[nt] = Bp[(ntb + nt) * 64 + lane];
#pragma unroll
    for (int ks = 0; ks < 4; ++ks) {
      if (ks < 3) {
#pragma unroll
        for (int nt = 0; nt < 4; ++nt) bnxt[nt] = Bp[(ks + 1) * 512 + (ntb + nt) * 64 + lane];
      }
#pragma unroll
      for (int nt = 0; nt < 4; ++nt)
        acc[nt] = __builtin_amdgcn_mfma_f32_16x16x32_bf16(a_[ks], bcur[nt], acc[nt], 0, 0, 0);
      if (ks < 3) {
#pragma unroll
        for (int nt = 0; nt < 4; ++nt) bcur[nt] = bnxt[nt];
      }
    }
  }
  int hi = lane >> 4, c = lane & 15;
#pragma unroll
  for (int nt = 0; nt < 4; ++nt) {
    int col = (ntb + nt) * 16 + c;
    float b = bias[col];
#pragma unroll
    for (int rr = 0; rr < 4; ++rr) {
      int row = rb + hi * 4 + rr;
      float v = fmaxf(acc[nt][rr] + b, 0.f);
      C[(size_t)row * HID + col] = v;
    }
  }
}

// ---------------- BatchNorm normalize: fp32 h -> bf16 hb ----------------
__global__ void bn_norm_k(const float* __restrict__ H, unsigned short* __restrict__ HB,
                          const float* __restrict__ stats, const float* __restrict__ gamma,
                          const float* __restrict__ beta) {
  int i = blockIdx.x * 256 + threadIdx.x;
  if (i >= NNODES * 32) return;
  int c4 = i & 31;
  float4 v = ((const float4*)H)[i];
  float4 sm = ((const float4*)stats)[c4];
  float4 sq = ((const float4*)(stats + 128))[c4];
  float4 g = ((const float4*)gamma)[c4];
  float4 bt = ((const float4*)beta)[c4];
  const float invN = 1.0f / (float)NNODES;
  float m, var, inv;
  ushort4 o;
  m = sm.x * invN; var = sq.x * invN - m * m; inv = rsqrtf(var + BN_EPS);
  o.x = f2bf((v.x - m) * inv * g.x + bt.x);
  m = sm.y * invN; var = sq.y * invN - m * m; inv = rsqrtf(var + BN_EPS);
  o.y = f2bf((v.y - m) * inv * g.y + bt.y);
  m = sm.z * invN; var = sq.z * invN - m * m; inv = rsqrtf(var + BN_EPS);
  o.z = f2bf((v.z - m) * inv * g.z + bt.z);
  m = sm.w * invN; var = sq.w * invN - m * m; inv = rsqrtf(var + BN_EPS);
  o.w = f2bf((v.w - m) * inv * g.w + bt.w);
  ((ushort4*)HB)[i] = o;
}

// ---------------- head: out[M,8] = t2[M,128] @ W[128,8] + b ----------------
__global__ void head_k(const float* __restrict__ O1, const float* __restrict__ W,
                       const float* __restrict__ b, float* __restrict__ out, int M) {
  __shared__ float sW[HID * NOUT];
  int tid = threadIdx.x;
#pragma unroll
  for (int i = 0; i < 4; ++i) sW[tid + i * 256] = W[tid + i * 256];
  __syncthreads();
  int row = blockIdx.x * 256 + tid;
  if (row >= M) return;
  float acc[NOUT];
#pragma unroll
  for (int j = 0; j < NOUT; ++j) acc[j] = b[j];
  const float* Ar = O1 + (size_t)row * HID;
  for (int k = 0; k < HID; k += 4) {
    float4 a = *(const float4*)(Ar + k);
#pragma unroll
    for (int kk = 0; kk < 4; ++kk) {
      float av = ((const float*)&a)[kk];
#pragma unroll
      for (int j = 0; j < NOUT; ++j) acc[j] += av * sW[(k + kk) * NOUT + j];
    }
  }
#pragma unroll
  for (int j = 0; j < NOUT; ++j) out[(size_t)row * NOUT + j] = acc[j];
}

// ---------------- launch ----------------

extern "C" void kernel_launch(void* const* d_in, const int* in_sizes, int n_in,
                              void* d_out, int out_size, void* d_ws, size_t ws_size,
                              hipStream_t stream) {
  const float* x     = (const float*)d_in[0];
  const int*   ei    = (const int*)d_in[1];
  const float* W1    = (const float*)d_in[2];
  const float* b1    = (const float*)d_in[3];
  const float* W2    = (const float*)d_in[4];
  const float* b2    = (const float*)d_in[5];
  const float* gamma = (const float*)d_in[6];
  const float* beta  = (const float*)d_in[7];
  const float* l1W   = (const float*)d_in[8];
  const float* l1b   = (const float*)d_in[9];
  const float* l2W   = (const float*)d_in[10];
  const float* l2b   = (const float*)d_in[11];

  float* ws = (float*)d_ws;
  const size_t NB = (size_t)NNODES * HID;    // 6.4e6 elements
  const size_t NBH = NB / 2;                 // bf16 buffer size in float units
  float* h = ws;                             // fp32 pre-BN (reused each layer)
  float* t2 = ws + NB;                       // fp32 jk output
  unsigned short* xb = (unsigned short*)(ws + 2 * NB);            // bf16 x
  unsigned short* tmp = (unsigned short*)(ws + 2 * NB + NBH);     // bf16 agg out
  unsigned short* hb[4];
  for (int l = 0; l < 4; ++l)
    hb[l] = (unsigned short*)(ws + 2 * NB + (2 + l) * NBH);  // bf16 post-BN
  float* stats = ws + 2 * NB + 6 * NBH;
  int* flag = (int*)(stats + 1024);
  int* deg = flag + 4;
  int* off = deg + (NNODES + 1);
  int* cursor = off + (NNODES + 1);
  int* bsum = cursor + (NNODES + 1);
  int* boff = bsum + 256;
  int* srcs = boff + 260;
  size_t pofs = 2 * NB + 6 * NBH + 1024 + 4 + 3 * (size_t)(NNODES + 1) + 256 + 260 + NEDGES;
  pofs = (pofs + 3) & ~(size_t)3;  // 16B align
  unsigned short* P = (unsigned short*)(ws + pofs);
  // P: W1 layer l at l*16384; W2 layer l at 65536 + l*16384; lin1 at 131072.
  float* pstats = ws + pofs + 98304;  // NPBLK x 256 partial stats

  detect64_k<<<1, 256, 0, stream>>>(ei, flag);
  zero_deg_k<<<NBLK, 256, 0, stream>>>(deg);
  hist_k<<<2344, 256, 0, stream>>>(ei, flag, deg);
  blocksum_k<<<NBLK, 256, 0, stream>>>(deg, bsum);
  scanb_k<<<1, 256, 0, stream>>>(bsum, boff);
  writeoff_k<<<NBLK, 256, 0, stream>>>(deg, boff, off, cursor);
  fill_k<<<2344, 256, 0, stream>>>(ei, flag, cursor, srcs);
  packW_k<<<96, 256, 0, stream>>>(W1, W2, l1W, P);
  cvt_bf_k<<<6250, 256, 0, stream>>>(x, xb, NNODES * 32);

  const unsigned short* hin = xb;
  for (int l = 0; l < NLAYERS; ++l) {
    gather_agg_k<<<6250, 256, 0, stream>>>(hin, off, srcs, tmp);
    mlp_k<<<NPBLK, 128, 0, stream>>>(tmp, P + (size_t)l * 16384, b1 + l * HID,
                                     P + 65536 + (size_t)l * 16384, b2 + l * HID, h, NNODES,
                                     pstats);
    reduce_stats_k<<<256, 256, 0, stream>>>(pstats, stats + l * 256);
    bn_norm_k<<<6250, 256, 0, stream>>>(h, hb[l], stats + l * 256, gamma + l * HID,
                                        beta + l * HID);
    hin = hb[l];
  }
  mjkgemm_k<<<NPBLK, 128, 0, stream>>>(hb[0], hb[1], hb[2], hb[3], P + 131072, l1b, t2, NNODES);
  head_k<<<196, 256, 0, stream>>>(t2, l2W, l2b, (float*)d_out, NNODES);
}

// Round 12
// 353.184 us; speedup vs baseline: 1.4171x; 1.0653x over previous
//
#include <hip/hip_runtime.h>

#define NNODES 50000
#define NEDGES 600000
#define HID 128
#define NLAYERS 4
#define NOUT 8
#define BN_EPS 1e-5f
#define NBLK 196    // ceil(NNODES/256)
#define NPBLK 3125  // NNODES/16 — 16-row MFMA blocks (2 waves, N-split)
#define NCOPY 8     // histogram copies (XCD-affine via blockIdx%8)

typedef short short8 __attribute__((ext_vector_type(8)));
typedef float f32x4 __attribute__((ext_vector_type(4)));

__device__ inline unsigned short f2bf(float f) {
  unsigned u = __float_as_uint(f);
  unsigned r = ((u >> 16) & 1u) + 0x7fffu;
  return (unsigned short)((u + r) >> 16);
}
__device__ inline float bflo(unsigned w) { return __uint_as_float(w << 16); }
__device__ inline float bfhi(unsigned w) { return __uint_as_float(w & 0xffff0000u); }

// ---------------- utility kernels ----------------

// Detect whether edge_index arrived as int64 (odd int32 words all zero) or int32.
__global__ void detect64_k(const int* __restrict__ ei, int* __restrict__ flag) {
  __shared__ int anynz;
  if (threadIdx.x == 0) anynz = 0;
  __syncthreads();
  int acc = 0;
  for (int i = threadIdx.x; i < 4096; i += 256) {
    int p = i * 146;
    acc |= ei[2 * p + 1];
  }
  if (acc != 0) anynz = 1;
  __syncthreads();
  if (threadIdx.x == 0) *flag = (anynz == 0) ? 1 : 0;  // 1 => int64 layout
}

// fp32 -> bf16 convert (for the input x gather table)
__global__ void cvt_bf_k(const float* __restrict__ src, unsigned short* __restrict__ dst,
                         int n4) {
  int i = blockIdx.x * 256 + threadIdx.x;
  if (i >= n4) return;
  float4 v = ((const float4*)src)[i];
  ushort4 o;
  o.x = f2bf(v.x);
  o.y = f2bf(v.y);
  o.z = f2bf(v.z);
  o.w = f2bf(v.w);
  ((ushort4*)dst)[i] = o;
}

// ---------------- CSR build (8-copy histogram, rank capture, no-atomic fill) --------

__global__ void zero_degc_k(int* __restrict__ degC) {
  int i = blockIdx.x * 256 + threadIdx.x;
  if (i < NCOPY * NNODES) degC[i] = 0;
}

// Pass A: per-copy histogram + per-edge rank within (copy, dst).
__global__ void hist_rank_k(const int* __restrict__ ei, const int* __restrict__ flag,
                            int* __restrict__ degC, int* __restrict__ rank) {
  int e = blockIdx.x * 256 + threadIdx.x;
  if (e >= NEDGES) return;
  int d = (*flag) ? ei[2 * NEDGES + 2 * e] : ei[NEDGES + e];
  int c = blockIdx.x & (NCOPY - 1);
  rank[e] = atomicAdd(&degC[c * NNODES + d], 1);
}

// Pass B: per-node exclusive prefix across copies (in place) + total degree.
__global__ void coff_k(int* __restrict__ degC, int* __restrict__ deg) {
  int d = blockIdx.x * 256 + threadIdx.x;
  if (d >= NNODES) return;
  int run = 0;
#pragma unroll
  for (int c = 0; c < NCOPY; ++c) {
    int t = degC[c * NNODES + d];
    degC[c * NNODES + d] = run;
    run += t;
  }
  deg[d] = run;
}

// Scan phase A: per-block (256-chunk) sums.
__global__ void blocksum_k(const int* __restrict__ deg, int* __restrict__ bsum) {
  int t = threadIdx.x;
  int i = blockIdx.x * 256 + t;
  __shared__ int sh[256];
  sh[t] = (i < NNODES) ? deg[i] : 0;
  __syncthreads();
  for (int s = 128; s > 0; s >>= 1) {
    if (t < s) sh[t] += sh[t + s];
    __syncthreads();
  }
  if (t == 0) bsum[blockIdx.x] = sh[0];
}

// Scan phase B: single-block exclusive scan of the NBLK block sums.
__global__ void scanb_k(const int* __restrict__ bsum, int* __restrict__ boff) {
  __shared__ int sh[256];
  int t = threadIdx.x;
  sh[t] = (t < NBLK) ? bsum[t] : 0;
  __syncthreads();
  for (int d = 1; d < 256; d <<= 1) {
    int v = (t >= d) ? sh[t - d] : 0;
    __syncthreads();
    sh[t] += v;
    __syncthreads();
  }
  if (t < NBLK) boff[t] = (t == 0) ? 0 : sh[t - 1];
}

// Scan phase C: per-block exclusive scan + block offset -> off.
__global__ void writeoff_k(const int* __restrict__ deg, const int* __restrict__ boff,
                           int* __restrict__ off) {
  int t = threadIdx.x;
  int i = blockIdx.x * 256 + t;
  __shared__ int sh[256];
  int v = (i < NNODES) ? deg[i] : 0;
  sh[t] = v;
  __syncthreads();
  for (int d = 1; d < 256; d <<= 1) {
    int u = (t >= d) ? sh[t - d] : 0;
    __syncthreads();
    sh[t] += u;
    __syncthreads();
  }
  int excl = boff[blockIdx.x] + sh[t] - v;
  if (i < NNODES) off[i] = excl;
  if (i == NNODES - 1) off[NNODES] = excl + v;
}

// Pass D: fill with zero atomics (same block->copy mapping as pass A).
__global__ void fill2_k(const int* __restrict__ ei, const int* __restrict__ flag,
                        const int* __restrict__ off, const int* __restrict__ degC,
                        const int* __restrict__ rank, int* __restrict__ srcs) {
  int e = blockIdx.x * 256 + threadIdx.x;
  if (e >= NEDGES) return;
  int s, d;
  if (*flag) {
    s = ei[2 * e];
    d = ei[2 * NEDGES + 2 * e];
  } else {
    s = ei[e];
    d = ei[NEDGES + e];
  }
  int c = blockIdx.x & (NCOPY - 1);
  srcs[off[d] + degC[c * NNODES + d] + rank[e]] = s;
}

// ---------------- fused gather-aggregate (bf16 table -> bf16 out) ----------------
__global__ void gather_agg_k(const unsigned short* __restrict__ X,
                             const int* __restrict__ off, const int* __restrict__ srcs,
                             unsigned short* __restrict__ T) {
  int gid = blockIdx.x * 256 + threadIdx.x;
  int node = gid >> 5;
  if (node >= NNODES) return;
  int lane = gid & 31;
  int a = off[node], b = off[node + 1];
  const uint2* Xv = (const uint2*)X;
  uint2 w = Xv[(size_t)node * 32 + lane];
  float a0 = bflo(w.x), a1 = bfhi(w.x), a2 = bflo(w.y), a3 = bfhi(w.y);
  for (int base = a; base < b; base += 32) {
    int cnt = b - base;
    if (cnt > 32) cnt = 32;
    int idx = (lane < cnt) ? srcs[base + lane] : 0;
#pragma unroll 8
    for (int i = 0; i < cnt; ++i) {
      int s = __shfl(idx, i, 32);
      uint2 v = Xv[(size_t)s * 32 + lane];
      a0 += bflo(v.x);
      a1 += bfhi(v.x);
      a2 += bflo(v.y);
      a3 += bfhi(v.y);
    }
  }
  uint2 o;
  o.x = (unsigned)f2bf(a0) | ((unsigned)f2bf(a1) << 16);
  o.y = (unsigned)f2bf(a2) | ((unsigned)f2bf(a3) << 16);
  ((uint2*)T)[(size_t)node * 32 + lane] = o;
}

// ---------------- weight pre-pack into MFMA B-fragment layout ----------------
__global__ void packW_k(const float* __restrict__ W1, const float* __restrict__ W2,
                        const float* __restrict__ L1, unsigned short* __restrict__ P) {
  int t = blockIdx.x * 256 + threadIdx.x;
  if (t >= 48 * 512) return;
  int gk = t >> 9;
  int nt = (t >> 6) & 7;
  int lane = t & 63;
  const float* src;
  int kbase;
  if (gk < 16) {
    src = W1 + (gk >> 2) * 16384;
    kbase = (gk & 3) * 32;
  } else if (gk < 32) {
    src = W2 + ((gk - 16) >> 2) * 16384;
    kbase = ((gk - 16) & 3) * 32;
  } else {
    src = L1;
    kbase = (gk - 32) * 32;
  }
  int n = nt * 16 + (lane & 15);
  int k0 = kbase + (lane >> 4) * 8;
  unsigned short* dst = P + (size_t)t * 8;
#pragma unroll
  for (int j = 0; j < 8; ++j) dst[j] = f2bf(src[(size_t)(k0 + j) * HID + n]);
}

// ---------------- fused MLP: H = relu(relu(A@W1+b1)@W2+b2); stats -> pstats ----------
// 2 waves/block, 16 rows/block (N-split: wave w owns n-tiles 4w..4w+3), grid NPBLK.
__global__ __launch_bounds__(128) void mlp_k(const unsigned short* __restrict__ A,
                                             const unsigned short* __restrict__ P1,
                                             const float* __restrict__ bias1,
                                             const unsigned short* __restrict__ P2,
                                             const float* __restrict__ bias2,
                                             float* __restrict__ H, int M,
                                             float* __restrict__ pstats) {
  __shared__ unsigned short sA[16 * 136];  // 16x128 stage1->stage2 slab (+pad)
  int tid = threadIdx.x;
  int lane = tid & 63, w = tid >> 6;
  int rb = blockIdx.x * 16;  // NNODES % 16 == 0: no tail clamp needed
  int r = rb + (lane & 15);
  int hi = lane >> 4, c = lane & 15;
  int koff = hi * 8;
  int ntb = w * 4;  // this wave's n-tile base (cols 64w..64w+63)

  // hoisted A-row loads
  short8 a_[4];
  const unsigned short* Ar = A + (size_t)r * HID + koff;
#pragma unroll
  for (int ks = 0; ks < 4; ++ks) a_[ks] = *(const short8*)(Ar + ks * 32);

  const short8* Bp1 = (const short8*)P1;
  f32x4 acc[4];
#pragma unroll
  for (int nt = 0; nt < 4; ++nt) acc[nt] = (f32x4){0.f, 0.f, 0.f, 0.f};
  short8 bcur[4], bnxt[4];
#pragma unroll
  for (int nt = 0; nt < 4; ++nt) bcur[nt] = Bp1[(ntb + nt) * 64 + lane];
#pragma unroll
  for (int ks = 0; ks < 4; ++ks) {
    if (ks < 3) {
#pragma unroll
      for (int nt = 0; nt < 4; ++nt) bnxt[nt] = Bp1[(ks + 1) * 512 + (ntb + nt) * 64 + lane];
    }
#pragma unroll
    for (int nt = 0; nt < 4; ++nt)
      acc[nt] = __builtin_amdgcn_mfma_f32_16x16x32_bf16(a_[ks], bcur[nt], acc[nt], 0, 0, 0);
    if (ks < 3) {
#pragma unroll
      for (int nt = 0; nt < 4; ++nt) bcur[nt] = bnxt[nt];
    }
  }
  // epilogue 1: relu + bf16 -> shared slab (wave-disjoint column halves)
#pragma unroll
  for (int nt = 0; nt < 4; ++nt) {
    int col = (ntb + nt) * 16 + c;
    float b = bias1[col];
#pragma unroll
    for (int rr = 0; rr < 4; ++rr) {
      float v = fmaxf(acc[nt][rr] + b, 0.f);
      sA[(hi * 4 + rr) * 136 + col] = f2bf(v);
    }
  }
  __syncthreads();

  // stage 2: A from slab (full k), B2 for own n-tiles
#pragma unroll
  for (int nt = 0; nt < 4; ++nt) acc[nt] = (f32x4){0.f, 0.f, 0.f, 0.f};
  const short8* Bp2 = (const short8*)P2;
#pragma unroll
  for (int nt = 0; nt < 4; ++nt) bcur[nt] = Bp2[(ntb + nt) * 64 + lane];
#pragma unroll
  for (int ks = 0; ks < 4; ++ks) {
    short8 af = *(const short8*)&sA[c * 136 + ks * 32 + koff];
    if (ks < 3) {
#pragma unroll
      for (int nt = 0; nt < 4; ++nt) bnxt[nt] = Bp2[(ks + 1) * 512 + (ntb + nt) * 64 + lane];
    }
#pragma unroll
    for (int nt = 0; nt < 4; ++nt)
      acc[nt] = __builtin_amdgcn_mfma_f32_16x16x32_bf16(af, bcur[nt], acc[nt], 0, 0, 0);
    if (ks < 3) {
#pragma unroll
      for (int nt = 0; nt < 4; ++nt) bcur[nt] = bnxt[nt];
    }
  }
  // epilogue 2: relu + fp32 write + BN stat partials (wave-disjoint cols -> no atomics)
  float* dst = pstats + (size_t)blockIdx.x * 256;
#pragma unroll
  for (int nt = 0; nt < 4; ++nt) {
    int col = (ntb + nt) * 16 + c;
    float b = bias2[col];
    float s = 0.f, q = 0.f;
#pragma unroll
    for (int rr = 0; rr < 4; ++rr) {
      int row = rb + hi * 4 + rr;
      float v = fmaxf(acc[nt][rr] + b, 0.f);
      H[(size_t)row * HID + col] = v;
      s += v;
      q += v * v;
    }
    s += __shfl_xor(s, 16, 64);
    q += __shfl_xor(q, 16, 64);
    s += __shfl_xor(s, 32, 64);
    q += __shfl_xor(q, 32, 64);
    if (hi == 0) {
      dst[col] = s;  // unique writer per column
      dst[128 + col] = q;
    }
  }
}

// ---------------- stats finalize: stats[j] = sum_b pstats[b][j] ----------------
__global__ void reduce_stats_k(const float* __restrict__ pstats, float* __restrict__ stats) {
  __shared__ float sh[256];
  int j = blockIdx.x;
  int t = threadIdx.x;
  float acc = 0.f;
  for (int b = t; b < NPBLK; b += 256) acc += pstats[(size_t)b * 256 + j];
  sh[t] = acc;
  __syncthreads();
  for (int s = 128; s > 0; s >>= 1) {
    if (t < s) sh[t] += sh[t + s];
    __syncthreads();
  }
  if (t == 0) stats[j] = sh[0];
}

// ---------------- MFMA JK GEMM: t2 = relu(concat(hb0..hb3) @ lin1_W + b), fp32 out ----
__global__ __launch_bounds__(128) void mjkgemm_k(const unsigned short* __restrict__ H0,
                                                 const unsigned short* __restrict__ H1,
                                                 const unsigned short* __restrict__ H2,
                                                 const unsigned short* __restrict__ H3,
                                                 const unsigned short* __restrict__ P,
                                                 const float* __restrict__ bias,
                                                 float* __restrict__ C, int M) {
  int tid = threadIdx.x;
  int lane = tid & 63, w = tid >> 6;
  int rb = blockIdx.x * 16;
  int r = rb + (lane & 15);
  int koff = (lane >> 4) * 8;
  int ntb = w * 4;
  f32x4 acc[4];
#pragma unroll
  for (int nt = 0; nt < 4; ++nt) acc[nt] = (f32x4){0.f, 0.f, 0.f, 0.f};
  const unsigned short* Hs[4] = {H0, H1, H2, H3};
  short8 bcur[4], bnxt[4];
  for (int l = 0; l < 4; ++l) {
    const short8* Bp = (const short8*)(P + l * 16384);
    short8 a_[4];
    const unsigned short* Ar = Hs[l] + (size_t)r * HID + koff;
#pragma unroll
    for (int ks = 0; ks < 4; ++ks) a_[ks] = *(const short8*)(Ar + ks * 32);
#pragma unroll
    for (int nt = 0; nt < 4; ++nt) bcur[nt] = Bp[(ntb + nt) * 64 + lane];
#pragma unroll
    for (int ks = 0; ks < 4; ++ks) {
      if (ks < 3) {
#pragma unroll
        for (int nt = 0; nt < 4; ++nt) bnxt[nt] = Bp[(ks + 1) * 512 + (ntb + nt) * 64 + lane];
      }
#pragma unroll
      for (int nt = 0; nt < 4; ++nt)
        acc[nt] = __builtin_amdgcn_mfma_f32_16x16x32_bf16(a_[ks], bcur[nt], acc[nt], 0, 0, 0);
      if (ks < 3) {
#pragma unroll
        for (int nt = 0; nt < 4; ++nt) bcur[nt] = bnxt[nt];
      }
    }
  }
  int hi = lane >> 4, c = lane & 15;
#pragma unroll
  for (int nt = 0; nt < 4; ++nt) {
    int col = (ntb + nt) * 16 + c;
    float b = bias[col];
#pragma unroll
    for (int rr = 0; rr < 4; ++rr) {
      int row = rb + hi * 4 + rr;
      float v = fmaxf(acc[nt][rr] + b, 0.f);
      C[(size_t)row * HID + col] = v;
    }
  }
}

// ---------------- BatchNorm normalize: fp32 h -> bf16 hb ----------------
__global__ void bn_norm_k(const float* __restrict__ H, unsigned short* __restrict__ HB,
                          const float* __restrict__ stats, const float* __restrict__ gamma,
                          const float* __restrict__ beta) {
  int i = blockIdx.x * 256 + threadIdx.x;
  if (i >= NNODES * 32) return;
  int c4 = i & 31;
  float4 v = ((const float4*)H)[i];
  float4 sm = ((const float4*)stats)[c4];
  float4 sq = ((const float4*)(stats + 128))[c4];
  float4 g = ((const float4*)gamma)[c4];
  float4 bt = ((const float4*)beta)[c4];
  const float invN = 1.0f / (float)NNODES;
  float m, var, inv;
  ushort4 o;
  m = sm.x * invN; var = sq.x * invN - m * m; inv = rsqrtf(var + BN_EPS);
  o.x = f2bf((v.x - m) * inv * g.x + bt.x);
  m = sm.y * invN; var = sq.y * invN - m * m; inv = rsqrtf(var + BN_EPS);
  o.y = f2bf((v.y - m) * inv * g.y + bt.y);
  m = sm.z * invN; var = sq.z * invN - m * m; inv = rsqrtf(var + BN_EPS);
  o.z = f2bf((v.z - m) * inv * g.z + bt.z);
  m = sm.w * invN; var = sq.w * invN - m * m; inv = rsqrtf(var + BN_EPS);
  o.w = f2bf((v.w - m) * inv * g.w + bt.w);
  ((ushort4*)HB)[i] = o;
}

// ---------------- head: out[M,8] = t2[M,128] @ W[128,8] + b ----------------
__global__ void head_k(const float* __restrict__ O1, const float* __restrict__ W,
                       const float* __restrict__ b, float* __restrict__ out, int M) {
  __shared__ float sW[HID * NOUT];
  int tid = threadIdx.x;
#pragma unroll
  for (int i = 0; i < 4; ++i) sW[tid + i * 256] = W[tid + i * 256];
  __syncthreads();
  int row = blockIdx.x * 256 + tid;
  if (row >= M) return;
  float acc[NOUT];
#pragma unroll
  for (int j = 0; j < NOUT; ++j) acc[j] = b[j];
  const float* Ar = O1 + (size_t)row * HID;
  for (int k = 0; k < HID; k += 4) {
    float4 a = *(const float4*)(Ar + k);
#pragma unroll
    for (int kk = 0; kk < 4; ++kk) {
      float av = ((const float*)&a)[kk];
#pragma unroll
      for (int j = 0; j < NOUT; ++j) acc[j] += av * sW[(k + kk) * NOUT + j];
    }
  }
#pragma unroll
  for (int j = 0; j < NOUT; ++j) out[(size_t)row * NOUT + j] = acc[j];
}

// ---------------- launch ----------------

extern "C" void kernel_launch(void* const* d_in, const int* in_sizes, int n_in,
                              void* d_out, int out_size, void* d_ws, size_t ws_size,
                              hipStream_t stream) {
  const float* x     = (const float*)d_in[0];
  const int*   ei    = (const int*)d_in[1];
  const float* W1    = (const float*)d_in[2];
  const float* b1    = (const float*)d_in[3];
  const float* W2    = (const float*)d_in[4];
  const float* b2    = (const float*)d_in[5];
  const float* gamma = (const float*)d_in[6];
  const float* beta  = (const float*)d_in[7];
  const float* l1W   = (const float*)d_in[8];
  const float* l1b   = (const float*)d_in[9];
  const float* l2W   = (const float*)d_in[10];
  const float* l2b   = (const float*)d_in[11];

  float* ws = (float*)d_ws;
  const size_t NB = (size_t)NNODES * HID;    // 6.4e6 elements
  const size_t NBH = NB / 2;                 // bf16 buffer size in float units
  float* h = ws;                             // fp32 pre-BN (reused each layer)
  float* t2 = ws + NB;                       // fp32 jk output
  unsigned short* xb = (unsigned short*)(ws + 2 * NB);            // bf16 x
  unsigned short* tmp = (unsigned short*)(ws + 2 * NB + NBH);     // bf16 agg out
  unsigned short* hb[4];
  for (int l = 0; l < 4; ++l)
    hb[l] = (unsigned short*)(ws + 2 * NB + (2 + l) * NBH);  // bf16 post-BN
  float* stats = ws + 2 * NB + 6 * NBH;
  int* flag = (int*)(stats + 1024);
  int* deg = flag + 4;
  int* off = deg + (NNODES + 1);
  int* bsum = off + (NNODES + 1);
  int* boff = bsum + 256;
  int* degC = boff + 260;              // NCOPY x NNODES
  int* rank = degC + NCOPY * NNODES;   // NEDGES
  int* srcs = rank + NEDGES;           // NEDGES
  size_t pofs = 2 * NB + 6 * NBH + 1024 + 4 + 2 * (size_t)(NNODES + 1) + 256 + 260 +
                (size_t)NCOPY * NNODES + 2 * (size_t)NEDGES;
  pofs = (pofs + 3) & ~(size_t)3;  // 16B align
  unsigned short* P = (unsigned short*)(ws + pofs);
  // P: W1 layer l at l*16384; W2 layer l at 65536 + l*16384; lin1 at 131072.
  float* pstats = ws + pofs + 98304;  // NPBLK x 256 partial stats

  detect64_k<<<1, 256, 0, stream>>>(ei, flag);
  zero_degc_k<<<1563, 256, 0, stream>>>(degC);
  hist_rank_k<<<2344, 256, 0, stream>>>(ei, flag, degC, rank);
  coff_k<<<NBLK, 256, 0, stream>>>(degC, deg);
  blocksum_k<<<NBLK, 256, 0, stream>>>(deg, bsum);
  scanb_k<<<1, 256, 0, stream>>>(bsum, boff);
  writeoff_k<<<NBLK, 256, 0, stream>>>(deg, boff, off);
  fill2_k<<<2344, 256, 0, stream>>>(ei, flag, off, degC, rank, srcs);
  packW_k<<<96, 256, 0, stream>>>(W1, W2, l1W, P);
  cvt_bf_k<<<6250, 256, 0, stream>>>(x, xb, NNODES * 32);

  const unsigned short* hin = xb;
  for (int l = 0; l < NLAYERS; ++l) {
    gather_agg_k<<<6250, 256, 0, stream>>>(hin, off, srcs, tmp);
    mlp_k<<<NPBLK, 128, 0, stream>>>(tmp, P + (size_t)l * 16384, b1 + l * HID,
                                     P + 65536 + (size_t)l * 16384, b2 + l * HID, h, NNODES,
                                     pstats);
    reduce_stats_k<<<256, 256, 0, stream>>>(pstats, stats + l * 256);
    bn_norm_k<<<6250, 256, 0, stream>>>(h, hb[l], stats + l * 256, gamma + l * HID,
                                        beta + l * HID);
    hin = hb[l];
  }
  mjkgemm_k<<<NPBLK, 128, 0, stream>>>(hb[0], hb[1], hb[2], hb[3], P + 131072, l1b, t2, NNODES);
  head_k<<<196, 256, 0, stream>>>(t2, l2W, l2b, (float*)d_out, NNODES);
}

// Round 13
// 327.882 us; speedup vs baseline: 1.5265x; 1.0772x over previous
//
#include <hip/hip_runtime.h>

#define NNODES 50000
#define NEDGES 600000
#define HID 128
#define NLAYERS 4
#define NOUT 8
#define BN_EPS 1e-5f
#define NBLK 196    // ceil(NNODES/256)
#define NPBLK 3125  // NNODES/16 — 16-row MFMA blocks (2 waves, N-split)
#define NCOPY 8     // histogram copies (XCD-affine via blockIdx%8)
#define IDXCAP 1024 // staged edge-index capacity per gather block

typedef short short8 __attribute__((ext_vector_type(8)));
typedef float f32x4 __attribute__((ext_vector_type(4)));

__device__ inline unsigned short f2bf(float f) {
  unsigned u = __float_as_uint(f);
  unsigned r = ((u >> 16) & 1u) + 0x7fffu;
  return (unsigned short)((u + r) >> 16);
}
__device__ inline float bflo(unsigned w) { return __uint_as_float(w << 16); }
__device__ inline float bfhi(unsigned w) { return __uint_as_float(w & 0xffff0000u); }

// ---------------- utility kernels ----------------

// Detect whether edge_index arrived as int64 (odd int32 words all zero) or int32.
__global__ void detect64_k(const int* __restrict__ ei, int* __restrict__ flag) {
  __shared__ int anynz;
  if (threadIdx.x == 0) anynz = 0;
  __syncthreads();
  int acc = 0;
  for (int i = threadIdx.x; i < 4096; i += 256) {
    int p = i * 146;
    acc |= ei[2 * p + 1];
  }
  if (acc != 0) anynz = 1;
  __syncthreads();
  if (threadIdx.x == 0) *flag = (anynz == 0) ? 1 : 0;  // 1 => int64 layout
}

// fp32 -> bf16 convert (for the input x gather table)
__global__ void cvt_bf_k(const float* __restrict__ src, unsigned short* __restrict__ dst,
                         int n4) {
  int i = blockIdx.x * 256 + threadIdx.x;
  if (i >= n4) return;
  float4 v = ((const float4*)src)[i];
  ushort4 o;
  o.x = f2bf(v.x);
  o.y = f2bf(v.y);
  o.z = f2bf(v.z);
  o.w = f2bf(v.w);
  ((ushort4*)dst)[i] = o;
}

// ---------------- CSR build (8-copy histogram, rank capture, no-atomic fill) --------

__global__ void zero_degc_k(int* __restrict__ degC) {
  int i = blockIdx.x * 256 + threadIdx.x;
  if (i < NCOPY * NNODES) degC[i] = 0;
}

// Pass A: per-copy histogram + per-edge rank within (copy, dst).
__global__ void hist_rank_k(const int* __restrict__ ei, const int* __restrict__ flag,
                            int* __restrict__ degC, int* __restrict__ rank) {
  int e = blockIdx.x * 256 + threadIdx.x;
  if (e >= NEDGES) return;
  int d = (*flag) ? ei[2 * NEDGES + 2 * e] : ei[NEDGES + e];
  int c = blockIdx.x & (NCOPY - 1);
  rank[e] = atomicAdd(&degC[c * NNODES + d], 1);
}

// Pass B: per-node exclusive prefix across copies (in place) + total degree.
__global__ void coff_k(int* __restrict__ degC, int* __restrict__ deg) {
  int d = blockIdx.x * 256 + threadIdx.x;
  if (d >= NNODES) return;
  int run = 0;
#pragma unroll
  for (int c = 0; c < NCOPY; ++c) {
    int t = degC[c * NNODES + d];
    degC[c * NNODES + d] = run;
    run += t;
  }
  deg[d] = run;
}

// Scan phase A: per-block (256-chunk) sums.
__global__ void blocksum_k(const int* __restrict__ deg, int* __restrict__ bsum) {
  int t = threadIdx.x;
  int i = blockIdx.x * 256 + t;
  __shared__ int sh[256];
  sh[t] = (i < NNODES) ? deg[i] : 0;
  __syncthreads();
  for (int s = 128; s > 0; s >>= 1) {
    if (t < s) sh[t] += sh[t + s];
    __syncthreads();
  }
  if (t == 0) bsum[blockIdx.x] = sh[0];
}

// Scan phase B: single-block exclusive scan of the NBLK block sums.
__global__ void scanb_k(const int* __restrict__ bsum, int* __restrict__ boff) {
  __shared__ int sh[256];
  int t = threadIdx.x;
  sh[t] = (t < NBLK) ? bsum[t] : 0;
  __syncthreads();
  for (int d = 1; d < 256; d <<= 1) {
    int v = (t >= d) ? sh[t - d] : 0;
    __syncthreads();
    sh[t] += v;
    __syncthreads();
  }
  if (t < NBLK) boff[t] = (t == 0) ? 0 : sh[t - 1];
}

// Scan phase C: per-block exclusive scan + block offset -> off.
__global__ void writeoff_k(const int* __restrict__ deg, const int* __restrict__ boff,
                           int* __restrict__ off) {
  int t = threadIdx.x;
  int i = blockIdx.x * 256 + t;
  __shared__ int sh[256];
  int v = (i < NNODES) ? deg[i] : 0;
  sh[t] = v;
  __syncthreads();
  for (int d = 1; d < 256; d <<= 1) {
    int u = (t >= d) ? sh[t - d] : 0;
    __syncthreads();
    sh[t] += u;
    __syncthreads();
  }
  int excl = boff[blockIdx.x] + sh[t] - v;
  if (i < NNODES) off[i] = excl;
  if (i == NNODES - 1) off[NNODES] = excl + v;
}

// Pass D: fill with zero atomics (same block->copy mapping as pass A).
__global__ void fill2_k(const int* __restrict__ ei, const int* __restrict__ flag,
                        const int* __restrict__ off, const int* __restrict__ degC,
                        const int* __restrict__ rank, int* __restrict__ srcs) {
  int e = blockIdx.x * 256 + threadIdx.x;
  if (e >= NEDGES) return;
  int s, d;
  if (*flag) {
    s = ei[2 * e];
    d = ei[2 * NEDGES + 2 * e];
  } else {
    s = ei[e];
    d = ei[NEDGES + e];
  }
  int c = blockIdx.x & (NCOPY - 1);
  srcs[off[d] + degC[c * NNODES + d] + rank[e]] = s;
}

// ---------------- fused gather-aggregate (bf16 table -> bf16 out) ----------------
// 8 nodes/block. Block's off[] window and (contiguous!) srcs window staged into LDS:
// removes the per-node dependent idx-load latency and all shuffles — only the
// independent, pipelined row loads touch global in the inner loop.
__global__ void gather_agg_k(const unsigned short* __restrict__ X,
                             const int* __restrict__ off, const int* __restrict__ srcs,
                             unsigned short* __restrict__ T) {
  __shared__ int sOff[9];
  __shared__ int sIdx[IDXCAP];
  int tid = threadIdx.x;
  int nb = blockIdx.x * 8;
  if (tid < 9) sOff[tid] = off[nb + tid];
  __syncthreads();
  int base = sOff[0];
  int total = sOff[8] - base;
  int stage = total > IDXCAP ? IDXCAP : total;
  for (int t = tid; t < stage; t += 256) sIdx[t] = srcs[base + t];
  __syncthreads();

  int g = tid >> 5, lane = tid & 31;
  int node = nb + g;
  int a = sOff[g] - base, bnd = sOff[g + 1] - base;
  const uint2* Xv = (const uint2*)X;
  uint2 w = Xv[(size_t)node * 32 + lane];
  float a0 = bflo(w.x), a1 = bfhi(w.x), a2 = bflo(w.y), a3 = bfhi(w.y);

  if (total <= IDXCAP) {
    // fast path: all edge indices in LDS (broadcast reads, no conflicts)
    int e = a;
#pragma unroll
    for (; e + 4 <= bnd; e += 4) {
      int s0 = sIdx[e], s1 = sIdx[e + 1], s2 = sIdx[e + 2], s3 = sIdx[e + 3];
      uint2 v0 = Xv[(size_t)s0 * 32 + lane];
      uint2 v1 = Xv[(size_t)s1 * 32 + lane];
      uint2 v2 = Xv[(size_t)s2 * 32 + lane];
      uint2 v3 = Xv[(size_t)s3 * 32 + lane];
      a0 += bflo(v0.x); a1 += bfhi(v0.x); a2 += bflo(v0.y); a3 += bfhi(v0.y);
      a0 += bflo(v1.x); a1 += bfhi(v1.x); a2 += bflo(v1.y); a3 += bfhi(v1.y);
      a0 += bflo(v2.x); a1 += bfhi(v2.x); a2 += bflo(v2.y); a3 += bfhi(v2.y);
      a0 += bflo(v3.x); a1 += bfhi(v3.x); a2 += bflo(v3.y); a3 += bfhi(v3.y);
    }
    for (; e < bnd; ++e) {
      int s = sIdx[e];
      uint2 v = Xv[(size_t)s * 32 + lane];
      a0 += bflo(v.x); a1 += bfhi(v.x); a2 += bflo(v.y); a3 += bfhi(v.y);
    }
  } else {
    // rare slow path: indices straight from global (uniform address -> broadcast)
    for (int e = a; e < bnd; ++e) {
      int s = srcs[base + e];
      uint2 v = Xv[(size_t)s * 32 + lane];
      a0 += bflo(v.x); a1 += bfhi(v.x); a2 += bflo(v.y); a3 += bfhi(v.y);
    }
  }

  uint2 o;
  o.x = (unsigned)f2bf(a0) | ((unsigned)f2bf(a1) << 16);
  o.y = (unsigned)f2bf(a2) | ((unsigned)f2bf(a3) << 16);
  ((uint2*)T)[(size_t)node * 32 + lane] = o;
}

// ---------------- weight pre-pack into MFMA B-fragment layout ----------------
__global__ void packW_k(const float* __restrict__ W1, const float* __restrict__ W2,
                        const float* __restrict__ L1, unsigned short* __restrict__ P) {
  int t = blockIdx.x * 256 + threadIdx.x;
  if (t >= 48 * 512) return;
  int gk = t >> 9;
  int nt = (t >> 6) & 7;
  int lane = t & 63;
  const float* src;
  int kbase;
  if (gk < 16) {
    src = W1 + (gk >> 2) * 16384;
    kbase = (gk & 3) * 32;
  } else if (gk < 32) {
    src = W2 + ((gk - 16) >> 2) * 16384;
    kbase = ((gk - 16) & 3) * 32;
  } else {
    src = L1;
    kbase = (gk - 32) * 32;
  }
  int n = nt * 16 + (lane & 15);
  int k0 = kbase + (lane >> 4) * 8;
  unsigned short* dst = P + (size_t)t * 8;
#pragma unroll
  for (int j = 0; j < 8; ++j) dst[j] = f2bf(src[(size_t)(k0 + j) * HID + n]);
}

// ---------------- fused MLP: H = relu(relu(A@W1+b1)@W2+b2); stats -> pstats ----------
// 2 waves/block, 16 rows/block (N-split: wave w owns n-tiles 4w..4w+3), grid NPBLK.
__global__ __launch_bounds__(128) void mlp_k(const unsigned short* __restrict__ A,
                                             const unsigned short* __restrict__ P1,
                                             const float* __restrict__ bias1,
                                             const unsigned short* __restrict__ P2,
                                             const float* __restrict__ bias2,
                                             float* __restrict__ H, int M,
                                             float* __restrict__ pstats) {
  __shared__ unsigned short sA[16 * 136];  // 16x128 stage1->stage2 slab (+pad)
  int tid = threadIdx.x;
  int lane = tid & 63, w = tid >> 6;
  int rb = blockIdx.x * 16;  // NNODES % 16 == 0: no tail clamp needed
  int r = rb + (lane & 15);
  int hi = lane >> 4, c = lane & 15;
  int koff = hi * 8;
  int ntb = w * 4;  // this wave's n-tile base (cols 64w..64w+63)

  // hoisted A-row loads
  short8 a_[4];
  const unsigned short* Ar = A + (size_t)r * HID + koff;
#pragma unroll
  for (int ks = 0; ks < 4; ++ks) a_[ks] = *(const short8*)(Ar + ks * 32);

  const short8* Bp1 = (const short8*)P1;
  f32x4 acc[4];
#pragma unroll
  for (int nt = 0; nt < 4; ++nt) acc[nt] = (f32x4){0.f, 0.f, 0.f, 0.f};
  short8 bcur[4], bnxt[4];
#pragma unroll
  for (int nt = 0; nt < 4; ++nt) bcur[nt] = Bp1[(ntb + nt) * 64 + lane];
#pragma unroll
  for (int ks = 0; ks < 4; ++ks) {
    if (ks < 3) {
#pragma unroll
      for (int nt = 0; nt < 4; ++nt) bnxt[nt] = Bp1[(ks + 1) * 512 + (ntb + nt) * 64 + lane];
    }
#pragma unroll
    for (int nt = 0; nt < 4; ++nt)
      acc[nt] = __builtin_amdgcn_mfma_f32_16x16x32_bf16(a_[ks], bcur[nt], acc[nt], 0, 0, 0);
    if (ks < 3) {
#pragma unroll
      for (int nt = 0; nt < 4; ++nt) bcur[nt] = bnxt[nt];
    }
  }
  // epilogue 1: relu + bf16 -> shared slab (wave-disjoint column halves)
#pragma unroll
  for (int nt = 0; nt < 4; ++nt) {
    int col = (ntb + nt) * 16 + c;
    float b = bias1[col];
#pragma unroll
    for (int rr = 0; rr < 4; ++rr) {
      float v = fmaxf(acc[nt][rr] + b, 0.f);
      sA[(hi * 4 + rr) * 136 + col] = f2bf(v);
    }
  }
  __syncthreads();

  // stage 2: A from slab (full k), B2 for own n-tiles
#pragma unroll
  for (int nt = 0; nt < 4; ++nt) acc[nt] = (f32x4){0.f, 0.f, 0.f, 0.f};
  const short8* Bp2 = (const short8*)P2;
#pragma unroll
  for (int nt = 0; nt < 4; ++nt) bcur[nt] = Bp2[(ntb + nt) * 64 + lane];
#pragma unroll
  for (int ks = 0; ks < 4; ++ks) {
    short8 af = *(const short8*)&sA[c * 136 + ks * 32 + koff];
    if (ks < 3) {
#pragma unroll
      for (int nt = 0; nt < 4; ++nt) bnxt[nt] = Bp2[(ks + 1) * 512 + (ntb + nt) * 64 + lane];
    }
#pragma unroll
    for (int nt = 0; nt < 4; ++nt)
      acc[nt] = __builtin_amdgcn_mfma_f32_16x16x32_bf16(af, bcur[nt], acc[nt], 0, 0, 0);
    if (ks < 3) {
#pragma unroll
      for (int nt = 0; nt < 4; ++nt) bcur[nt] = bnxt[nt];
    }
  }
  // epilogue 2: relu + fp32 write + BN stat partials (wave-disjoint cols -> no atomics)
  float* dst = pstats + (size_t)blockIdx.x * 256;
#pragma unroll
  for (int nt = 0; nt < 4; ++nt) {
    int col = (ntb + nt) * 16 + c;
    float b = bias2[col];
    float s = 0.f, q = 0.f;
#pragma unroll
    for (int rr = 0; rr < 4; ++rr) {
      int row = rb + hi * 4 + rr;
      float v = fmaxf(acc[nt][rr] + b, 0.f);
      H[(size_t)row * HID + col] = v;
      s += v;
      q += v * v;
    }
    s += __shfl_xor(s, 16, 64);
    q += __shfl_xor(q, 16, 64);
    s += __shfl_xor(s, 32, 64);
    q += __shfl_xor(q, 32, 64);
    if (hi == 0) {
      dst[col] = s;  // unique writer per column
      dst[128 + col] = q;
    }
  }
}

// ---------------- stats finalize: stats[j] = sum_b pstats[b][j] ----------------
__global__ void reduce_stats_k(const float* __restrict__ pstats, float* __restrict__ stats) {
  __shared__ float sh[256];
  int j = blockIdx.x;
  int t = threadIdx.x;
  float acc = 0.f;
  for (int b = t; b < NPBLK; b += 256) acc += pstats[(size_t)b * 256 + j];
  sh[t] = acc;
  __syncthreads();
  for (int s = 128; s > 0; s >>= 1) {
    if (t < s) sh[t] += sh[t + s];
    __syncthreads();
  }
  if (t == 0) stats[j] = sh[0];
}

// ---------------- MFMA JK GEMM: t2 = relu(concat(hb0..hb3) @ lin1_W + b), fp32 out ----
__global__ __launch_bounds__(128) void mjkgemm_k(const unsigned short* __restrict__ H0,
                                                 const unsigned short* __restrict__ H1,
                                                 const unsigned short* __restrict__ H2,
                                                 const unsigned short* __restrict__ H3,
                                                 const unsigned short* __restrict__ P,
                                                 const float* __restrict__ bias,
                                                 float* __restrict__ C, int M) {
  int tid = threadIdx.x;
  int lane = tid & 63, w = tid >> 6;
  int rb = blockIdx.x * 16;
  int r = rb + (lane & 15);
  int koff = (lane >> 4) * 8;
  int ntb = w * 4;
  f32x4 acc[4];
#pragma unroll
  for (int nt = 0; nt < 4; ++nt) acc[nt] = (f32x4){0.f, 0.f, 0.f, 0.f};
  const unsigned short* Hs[4] = {H0, H1, H2, H3};
  short8 bcur[4], bnxt[4];
  for (int l = 0; l < 4; ++l) {
    const short8* Bp = (const short8*)(P + l * 16384);
    short8 a_[4];
    const unsigned short* Ar = Hs[l] + (size_t)r * HID + koff;
#pragma unroll
    for (int ks = 0; ks < 4; ++ks) a_[ks] = *(const short8*)(Ar + ks * 32);
#pragma unroll
    for (int nt = 0; nt < 4; ++nt) bcur[nt] = Bp[(ntb + nt) * 64 + lane];
#pragma unroll
    for (int ks = 0; ks < 4; ++ks) {
      if (ks < 3) {
#pragma unroll
        for (int nt = 0; nt < 4; ++nt) bnxt[nt] = Bp[(ks + 1) * 512 + (ntb + nt) * 64 + lane];
      }
#pragma unroll
      for (int nt = 0; nt < 4; ++nt)
        acc[nt] = __builtin_amdgcn_mfma_f32_16x16x32_bf16(a_[ks], bcur[nt], acc[nt], 0, 0, 0);
      if (ks < 3) {
#pragma unroll
        for (int nt = 0; nt < 4; ++nt) bcur[nt] = bnxt[nt];
      }
    }
  }
  int hi = lane >> 4, c = lane & 15;
#pragma unroll
  for (int nt = 0; nt < 4; ++nt) {
    int col = (ntb + nt) * 16 + c;
    float b = bias[col];
#pragma unroll
    for (int rr = 0; rr < 4; ++rr) {
      int row = rb + hi * 4 + rr;
      float v = fmaxf(acc[nt][rr] + b, 0.f);
      C[(size_t)row * HID + col] = v;
    }
  }
}

// ---------------- BatchNorm normalize: fp32 h -> bf16 hb ----------------
__global__ void bn_norm_k(const float* __restrict__ H, unsigned short* __restrict__ HB,
                          const float* __restrict__ stats, const float* __restrict__ gamma,
                          const float* __restrict__ beta) {
  int i = blockIdx.x * 256 + threadIdx.x;
  if (i >= NNODES * 32) return;
  int c4 = i & 31;
  float4 v = ((const float4*)H)[i];
  float4 sm = ((const float4*)stats)[c4];
  float4 sq = ((const float4*)(stats + 128))[c4];
  float4 g = ((const float4*)gamma)[c4];
  float4 bt = ((const float4*)beta)[c4];
  const float invN = 1.0f / (float)NNODES;
  float m, var, inv;
  ushort4 o;
  m = sm.x * invN; var = sq.x * invN - m * m; inv = rsqrtf(var + BN_EPS);
  o.x = f2bf((v.x - m) * inv * g.x + bt.x);
  m = sm.y * invN; var = sq.y * invN - m * m; inv = rsqrtf(var + BN_EPS);
  o.y = f2bf((v.y - m) * inv * g.y + bt.y);
  m = sm.z * invN; var = sq.z * invN - m * m; inv = rsqrtf(var + BN_EPS);
  o.z = f2bf((v.z - m) * inv * g.z + bt.z);
  m = sm.w * invN; var = sq.w * invN - m * m; inv = rsqrtf(var + BN_EPS);
  o.w = f2bf((v.w - m) * inv * g.w + bt.w);
  ((ushort4*)HB)[i] = o;
}

// ---------------- head: out[M,8] = t2[M,128] @ W[128,8] + b ----------------
__global__ void head_k(const float* __restrict__ O1, const float* __restrict__ W,
                       const float* __restrict__ b, float* __restrict__ out, int M) {
  __shared__ float sW[HID * NOUT];
  int tid = threadIdx.x;
#pragma unroll
  for (int i = 0; i < 4; ++i) sW[tid + i * 256] = W[tid + i * 256];
  __syncthreads();
  int row = blockIdx.x * 256 + tid;
  if (row >= M) return;
  float acc[NOUT];
#pragma unroll
  for (int j = 0; j < NOUT; ++j) acc[j] = b[j];
  const float* Ar = O1 + (size_t)row * HID;
  for (int k = 0; k < HID; k += 4) {
    float4 a = *(const float4*)(Ar + k);
#pragma unroll
    for (int kk = 0; kk < 4; ++kk) {
      float av = ((const float*)&a)[kk];
#pragma unroll
      for (int j = 0; j < NOUT; ++j) acc[j] += av * sW[(k + kk) * NOUT + j];
    }
  }
#pragma unroll
  for (int j = 0; j < NOUT; ++j) out[(size_t)row * NOUT + j] = acc[j];
}

// ---------------- launch ----------------

extern "C" void kernel_launch(void* const* d_in, const int* in_sizes, int n_in,
                              void* d_out, int out_size, void* d_ws, size_t ws_size,
                              hipStream_t stream) {
  const float* x     = (const float*)d_in[0];
  const int*   ei    = (const int*)d_in[1];
  const float* W1    = (const float*)d_in[2];
  const float* b1    = (const float*)d_in[3];
  const float* W2    = (const float*)d_in[4];
  const float* b2    = (const float*)d_in[5];
  const float* gamma = (const float*)d_in[6];
  const float* beta  = (const float*)d_in[7];
  const float* l1W   = (const float*)d_in[8];
  const float* l1b   = (const float*)d_in[9];
  const float* l2W   = (const float*)d_in[10];
  const float* l2b   = (const float*)d_in[11];

  float* ws = (float*)d_ws;
  const size_t NB = (size_t)NNODES * HID;    // 6.4e6 elements
  const size_t NBH = NB / 2;                 // bf16 buffer size in float units
  float* h = ws;                             // fp32 pre-BN (reused each layer)
  float* t2 = ws + NB;                       // fp32 jk output
  unsigned short* xb = (unsigned short*)(ws + 2 * NB);            // bf16 x
  unsigned short* tmp = (unsigned short*)(ws + 2 * NB + NBH);     // bf16 agg out
  unsigned short* hb[4];
  for (int l = 0; l < 4; ++l)
    hb[l] = (unsigned short*)(ws + 2 * NB + (2 + l) * NBH);  // bf16 post-BN
  float* stats = ws + 2 * NB + 6 * NBH;
  int* flag = (int*)(stats + 1024);
  int* deg = flag + 4;
  int* off = deg + (NNODES + 1);
  int* bsum = off + (NNODES + 1);
  int* boff = bsum + 256;
  int* degC = boff + 260;              // NCOPY x NNODES
  int* rank = degC + NCOPY * NNODES;   // NEDGES
  int* srcs = rank + NEDGES;           // NEDGES
  size_t pofs = 2 * NB + 6 * NBH + 1024 + 4 + 2 * (size_t)(NNODES + 1) + 256 + 260 +
                (size_t)NCOPY * NNODES + 2 * (size_t)NEDGES;
  pofs = (pofs + 3) & ~(size_t)3;  // 16B align
  unsigned short* P = (unsigned short*)(ws + pofs);
  // P: W1 layer l at l*16384; W2 layer l at 65536 + l*16384; lin1 at 131072.
  float* pstats = ws + pofs + 98304;  // NPBLK x 256 partial stats

  detect64_k<<<1, 256, 0, stream>>>(ei, flag);
  zero_degc_k<<<1563, 256, 0, stream>>>(degC);
  hist_rank_k<<<2344, 256, 0, stream>>>(ei, flag, degC, rank);
  coff_k<<<NBLK, 256, 0, stream>>>(degC, deg);
  blocksum_k<<<NBLK, 256, 0, stream>>>(deg, bsum);
  scanb_k<<<1, 256, 0, stream>>>(bsum, boff);
  writeoff_k<<<NBLK, 256, 0, stream>>>(deg, boff, off);
  fill2_k<<<2344, 256, 0, stream>>>(ei, flag, off, degC, rank, srcs);
  packW_k<<<96, 256, 0, stream>>>(W1, W2, l1W, P);
  cvt_bf_k<<<6250, 256, 0, stream>>>(x, xb, NNODES * 32);

  const unsigned short* hin = xb;
  for (int l = 0; l < NLAYERS; ++l) {
    gather_agg_k<<<6250, 256, 0, stream>>>(hin, off, srcs, tmp);
    mlp_k<<<NPBLK, 128, 0, stream>>>(tmp, P + (size_t)l * 16384, b1 + l * HID,
                                     P + 65536 + (size_t)l * 16384, b2 + l * HID, h, NNODES,
                                     pstats);
    reduce_stats_k<<<256, 256, 0, stream>>>(pstats, stats + l * 256);
    bn_norm_k<<<6250, 256, 0, stream>>>(h, hb[l], stats + l * 256, gamma + l * HID,
                                        beta + l * HID);
    hin = hb[l];
  }
  mjkgemm_k<<<NPBLK, 128, 0, stream>>>(hb[0], hb[1], hb[2], hb[3], P + 131072, l1b, t2, NNODES);
  head_k<<<196, 256, 0, stream>>>(t2, l2W, l2b, (float*)d_out, NNODES);
}